// Round 1
// baseline (1412.840 us; speedup 1.0000x reference)
//
#include <hip/hip_runtime.h>
#include <cstdint>
#include <cstddef>

#define LOG2E 1.442695040888963f

__device__ __forceinline__ float rdlane(float v, int lane) {
    return __int_as_float(__builtin_amdgcn_readlane(__float_as_int(v), lane));
}

template <int Q>
__device__ __forceinline__ float quad_bcast(float v) {
    // quad_perm broadcast of lane Q within each quad of 4 lanes
    return __int_as_float(__builtin_amdgcn_update_dpp(
        0, __float_as_int(v), Q * 0x55, 0xF, 0xF, true));
}

// Pad emb (V,15) -> embPad (V,16) so each row is one 64B-aligned block (4x s_load_dwordx4).
__global__ void pad_emb_kernel(const float* __restrict__ emb,
                               float* __restrict__ embPad, int V) {
    int i = blockIdx.x * 256 + threadIdx.x;
    if (i < V * 16) {
        int v = i >> 4, k = i & 15;
        embPad[i] = (k < 15) ? emb[v * 15 + k] : 0.0f;
    }
}

// One wave per (direction, sample). Lane = 4*j + g  (j = hidden unit 0..14, g = gate i/f/g/o).
// Hidden state h_j replicated across its quad; broadcast to all lanes via v_readlane -> SGPR FMA.
// Writes h into d_out[b][t][dir*15 + j] (cols 0..29 of the 45-wide output rows).
__global__ __launch_bounds__(64) void lstm_kernel(
    const int* __restrict__ data, const int* __restrict__ lengths,
    const float* __restrict__ embPad,
    const float* __restrict__ h0, const float* __restrict__ c0,
    const float* __restrict__ w_ih_f, const float* __restrict__ w_hh_f,
    const float* __restrict__ b_f,
    const float* __restrict__ w_ih_b, const float* __restrict__ w_hh_b,
    const float* __restrict__ b_b,
    float* __restrict__ out, int T) {
    const int lane = threadIdx.x;
    const int dir = blockIdx.x >> 6;
    const int b = blockIdx.x & 63;
    const int L = lengths[b];

    if (lane >= 60) return;   // single branch; exec stays 60 lanes for the whole loop

    const int j = lane >> 2;      // hidden unit 0..14
    const int g = lane & 3;       // 0=i 1=f 2=g(tanh) 3=o
    const int row = g * 15 + j;   // row in (4H, *) weights (torch gate order)

    const float* wih = dir ? w_ih_b : w_ih_f;
    const float* whh = dir ? w_hh_b : w_hh_f;
    const float* bv  = dir ? b_b   : b_f;

    // activation: act(z) = aa * rcp(1 + exp2(m*z)) + ab   (sigmoid or tanh)
    const float m  = (g == 2) ? (-2.0f * LOG2E) : (-LOG2E);
    const float aa = (g == 2) ? 2.0f : 1.0f;
    const float ab = (g == 2) ? -1.0f : 0.0f;

    float wx[15], wh[15];
    #pragma unroll
    for (int k = 0; k < 15; ++k) {
        wx[k] = wih[row * 15 + k] * m;   // fold activation pre-scale into weights
        wh[k] = whh[row * 15 + k] * m;
    }
    const float biasm = bv[row] * m;

    float h = h0[(dir * 64 + b) * 15 + j];   // replicated across quad
    float c = c0[(dir * 64 + b) * 15 + j];

    const int* drow = data + (size_t)b * T;
    float* outp = out + ((size_t)b * T) * 45 + dir * 15 + j;
    const int sgn  = dir ? -1 : 1;
    const int base = dir ? (L - 1) : 0;   // pos(t) = base + sgn*t

    auto tok = [&](int t) -> int {
        int tt = t < L ? t : L - 1;       // clamp prefetch past end
        return drow[base + sgn * tt];
    };

    auto step = [&](int pos, float4 x0, float4 x1, float4 x2, float4 x3) {
        float acc0 = biasm, acc1 = 0.f, acc2 = 0.f, acc3 = 0.f;
        float hk0 = rdlane(h, 0),  hk1 = rdlane(h, 4),  hk2 = rdlane(h, 8);
        float hk3 = rdlane(h, 12), hk4 = rdlane(h, 16), hk5 = rdlane(h, 20);
        float hk6 = rdlane(h, 24), hk7 = rdlane(h, 28), hk8 = rdlane(h, 32);
        float hk9 = rdlane(h, 36), hk10 = rdlane(h, 40), hk11 = rdlane(h, 44);
        float hk12 = rdlane(h, 48), hk13 = rdlane(h, 52), hk14 = rdlane(h, 56);
        acc0 = fmaf(hk0,  wh[0],  acc0);  acc1 = fmaf(hk1,  wh[1],  acc1);
        acc2 = fmaf(hk2,  wh[2],  acc2);  acc3 = fmaf(hk3,  wh[3],  acc3);
        acc0 = fmaf(hk4,  wh[4],  acc0);  acc1 = fmaf(hk5,  wh[5],  acc1);
        acc2 = fmaf(hk6,  wh[6],  acc2);  acc3 = fmaf(hk7,  wh[7],  acc3);
        acc0 = fmaf(hk8,  wh[8],  acc0);  acc1 = fmaf(hk9,  wh[9],  acc1);
        acc2 = fmaf(hk10, wh[10], acc2);  acc3 = fmaf(hk11, wh[11], acc3);
        acc0 = fmaf(hk12, wh[12], acc0);  acc1 = fmaf(hk13, wh[13], acc1);
        acc2 = fmaf(hk14, wh[14], acc2);
        acc3 = fmaf(x0.x, wx[0],  acc3);  acc0 = fmaf(x0.y, wx[1],  acc0);
        acc1 = fmaf(x0.z, wx[2],  acc1);  acc2 = fmaf(x0.w, wx[3],  acc2);
        acc3 = fmaf(x1.x, wx[4],  acc3);  acc0 = fmaf(x1.y, wx[5],  acc0);
        acc1 = fmaf(x1.z, wx[6],  acc1);  acc2 = fmaf(x1.w, wx[7],  acc2);
        acc3 = fmaf(x2.x, wx[8],  acc3);  acc0 = fmaf(x2.y, wx[9],  acc0);
        acc1 = fmaf(x2.z, wx[10], acc1);  acc2 = fmaf(x2.w, wx[11], acc2);
        acc3 = fmaf(x3.x, wx[12], acc3);  acc0 = fmaf(x3.y, wx[13], acc0);
        acc1 = fmaf(x3.z, wx[14], acc1);
        float z = (acc0 + acc1) + (acc2 + acc3);
        float u = __builtin_amdgcn_exp2f(z);
        float r = fmaf(aa, __builtin_amdgcn_rcpf(1.0f + u), ab);  // activated gate
        float vi = quad_bcast<0>(r);
        float vf = quad_bcast<1>(r);
        float vg = quad_bcast<2>(r);
        float vo = quad_bcast<3>(r);
        c = fmaf(vf, c, vi * vg);
        float u2 = __builtin_amdgcn_exp2f(c * (-2.0f * LOG2E));
        float th = fmaf(2.0f, __builtin_amdgcn_rcpf(1.0f + u2), -1.0f);
        h = vo * th;                       // replicated in quad; 4 lanes store same value
        outp[(size_t)pos * 45] = h;
    };

    // software pipeline: x rows 2 steps ahead, tokens 4 ahead (uniform -> s_load)
    int kA = tok(0), kB = tok(1);
    const float4* eA = (const float4*)(embPad + (size_t)kA * 16);
    float4 A0 = eA[0], A1 = eA[1], A2 = eA[2], A3 = eA[3];
    const float4* eB = (const float4*)(embPad + (size_t)kB * 16);
    float4 B0 = eB[0], B1 = eB[1], B2 = eB[2], B3 = eB[3];
    kA = tok(2); kB = tok(3);

    int t = 0;
    for (; t + 2 <= L; t += 2) {
        step(base + sgn * t, A0, A1, A2, A3);
        {
            const float4* e = (const float4*)(embPad + (size_t)kA * 16);
            A0 = e[0]; A1 = e[1]; A2 = e[2]; A3 = e[3];
            kA = tok(t + 4);
        }
        step(base + sgn * (t + 1), B0, B1, B2, B3);
        {
            const float4* e = (const float4*)(embPad + (size_t)kB * 16);
            B0 = e[0]; B1 = e[1]; B2 = e[2]; B3 = e[3];
            kB = tok(t + 5);
        }
    }
    if (t < L) step(base + sgn * t, A0, A1, A2, A3);
}

// Epilogue: in-place linear 30 -> 45 per (b,t) row; rows t >= L get just lin_b.
__global__ __launch_bounds__(256) void linear_kernel(
    const int* __restrict__ lengths,
    const float* __restrict__ lin_w, const float* __restrict__ lin_b,
    float* out, int T) {
    __shared__ float Ws[45 * 30];
    __shared__ float Bs[45];
    for (int i = threadIdx.x; i < 45 * 30; i += 256) Ws[i] = lin_w[i];
    if (threadIdx.x < 45) Bs[threadIdx.x] = lin_b[threadIdx.x];
    __syncthreads();
    const int b = blockIdx.y;
    const int t = blockIdx.x * 256 + threadIdx.x;
    if (t >= T) return;
    const int L = lengths[b];
    float* row = out + ((size_t)b * T + t) * 45;
    float y[45];
    if (t < L) {
        float x[30];
        #pragma unroll
        for (int k = 0; k < 30; ++k) x[k] = row[k];
        #pragma unroll
        for (int o = 0; o < 45; ++o) {
            float acc = Bs[o];
            #pragma unroll
            for (int k = 0; k < 30; ++k) acc = fmaf(x[k], Ws[o * 30 + k], acc);
            y[o] = acc;
        }
    } else {
        #pragma unroll
        for (int o = 0; o < 45; ++o) y[o] = Bs[o];
    }
    #pragma unroll
    for (int o = 0; o < 45; ++o) row[o] = y[o];
}

extern "C" void kernel_launch(void* const* d_in, const int* in_sizes, int n_in,
                              void* d_out, int out_size, void* d_ws, size_t ws_size,
                              hipStream_t stream) {
    const int* data      = (const int*)d_in[0];
    // d_in[1] = innerSize (== T), derived from in_sizes instead
    const int* lengths   = (const int*)d_in[2];
    const float* emb     = (const float*)d_in[3];
    const float* h0      = (const float*)d_in[4];
    const float* c0      = (const float*)d_in[5];
    const float* w_ih_f  = (const float*)d_in[6];
    const float* w_hh_f  = (const float*)d_in[7];
    const float* b_f     = (const float*)d_in[8];
    const float* w_ih_b  = (const float*)d_in[9];
    const float* w_hh_b  = (const float*)d_in[10];
    const float* b_b     = (const float*)d_in[11];
    const float* lin_w   = (const float*)d_in[12];
    const float* lin_b   = (const float*)d_in[13];
    float* out = (float*)d_out;

    const int T = in_sizes[0] / 64;
    const int V = in_sizes[3] / 15;
    float* embPad = (float*)d_ws;   // V*16 floats = 3.2 MB

    hipLaunchKernelGGL(pad_emb_kernel, dim3((V * 16 + 255) / 256), dim3(256), 0, stream,
                       emb, embPad, V);
    hipLaunchKernelGGL(lstm_kernel, dim3(128), dim3(64), 0, stream,
                       data, lengths, embPad, h0, c0,
                       w_ih_f, w_hh_f, b_f, w_ih_b, w_hh_b, b_b, out, T);
    hipLaunchKernelGGL(linear_kernel, dim3((T + 255) / 256, 64), dim3(256), 0, stream,
                       lengths, lin_w, lin_b, out, T);
}

// Round 2
// 723.240 us; speedup vs baseline: 1.9535x; 1.9535x over previous
//
#include <hip/hip_runtime.h>
#include <cstdint>
#include <cstddef>

#define LOG2E 1.442695040888963f

__device__ __forceinline__ float rdlane(float v, int lane) {
    return __int_as_float(__builtin_amdgcn_readlane(__float_as_int(v), lane));
}

template <int Q>
__device__ __forceinline__ float quad_bcast(float v) {
    // quad_perm broadcast of lane Q within each quad of 4 lanes
    return __int_as_float(__builtin_amdgcn_update_dpp(
        0, __float_as_int(v), Q * 0x55, 0xF, 0xF, true));
}

// Precompute per-token gate inputs: proj[d][v][s] = m(s) * (b[row] + W_ih[row,:] . emb[v,:])
// s = 4*j + g lane-slot order, row = g*15+j (torch gate order i,f,g,o), stride 64 floats/row.
__global__ __launch_bounds__(256) void proj_kernel(
    const float* __restrict__ emb,
    const float* __restrict__ w_ih_f, const float* __restrict__ b_f,
    const float* __restrict__ w_ih_b, const float* __restrict__ b_b,
    float* __restrict__ proj, int V) {
    int gid = blockIdx.x * 256 + threadIdx.x;
    if (gid >= 2 * V * 64) return;
    int s = gid & 63;
    int v = (gid >> 6) % V;
    int d = gid / (V * 64);
    if (s >= 60) { proj[gid] = 0.0f; return; }
    int j = s >> 2, g = s & 3;
    int row = g * 15 + j;
    const float* w  = d ? w_ih_b : w_ih_f;
    const float* bv = d ? b_b   : b_f;
    float m = (g == 2) ? (-2.0f * LOG2E) : (-LOG2E);
    float acc = bv[row];
    #pragma unroll
    for (int k = 0; k < 15; ++k)
        acc = fmaf(emb[v * 15 + k], w[row * 15 + k], acc);
    proj[gid] = m * acc;
}

// One wave per (direction, sample). Lane = 4*j + g. Per-step memory: one dword/lane
// from proj (prefetched 8 steps ahead; token indices prefetched 16 ahead).
__global__ __launch_bounds__(64) void lstm_kernel(
    const int* __restrict__ data, const int* __restrict__ lengths,
    const float* __restrict__ proj,
    const float* __restrict__ h0, const float* __restrict__ c0,
    const float* __restrict__ w_hh_f, const float* __restrict__ w_hh_b,
    float* __restrict__ out, int T, int V) {
    const int lane = threadIdx.x;
    const int dir = blockIdx.x >> 6;
    const int b = blockIdx.x & 63;
    const int L = lengths[b];

    if (lane >= 60) return;   // exec stays 60 lanes for the whole loop

    const int j = lane >> 2;      // hidden unit 0..14
    const int g = lane & 3;       // 0=i 1=f 2=g(tanh) 3=o
    const int row = g * 15 + j;

    const float* whh = dir ? w_hh_b : w_hh_f;
    const float m  = (g == 2) ? (-2.0f * LOG2E) : (-LOG2E);
    const float aa = (g == 2) ? 2.0f : 1.0f;
    const float ab = (g == 2) ? -1.0f : 0.0f;

    float wh[15];
    #pragma unroll
    for (int k = 0; k < 15; ++k) wh[k] = whh[row * 15 + k] * m;

    float h = h0[(dir * 64 + b) * 15 + j];   // replicated across quad
    float c = c0[(dir * 64 + b) * 15 + j];

    const int* drow = data + (size_t)b * T;
    const float* pj = proj + (size_t)dir * V * 64 + lane;
    float* outp = out + ((size_t)b * T) * 45 + dir * 15 + j;
    const int sgn  = dir ? -1 : 1;
    const int base = dir ? (L - 1) : 0;   // pos(t) = base + sgn*t

    auto tok = [&](int t) -> int {
        int tt = t < L ? t : L - 1;       // clamp prefetch past end
        return drow[base + sgn * tt];
    };

    auto step = [&](int pos, float xg) {
        float hk0 = rdlane(h, 0),  hk1 = rdlane(h, 4),  hk2 = rdlane(h, 8);
        float hk3 = rdlane(h, 12), hk4 = rdlane(h, 16), hk5 = rdlane(h, 20);
        float hk6 = rdlane(h, 24), hk7 = rdlane(h, 28), hk8 = rdlane(h, 32);
        float hk9 = rdlane(h, 36), hk10 = rdlane(h, 40), hk11 = rdlane(h, 44);
        float hk12 = rdlane(h, 48), hk13 = rdlane(h, 52), hk14 = rdlane(h, 56);
        float acc0 = xg, acc1 = 0.f, acc2 = 0.f, acc3 = 0.f;
        acc0 = fmaf(hk0,  wh[0],  acc0);  acc1 = fmaf(hk1,  wh[1],  acc1);
        acc2 = fmaf(hk2,  wh[2],  acc2);  acc3 = fmaf(hk3,  wh[3],  acc3);
        acc0 = fmaf(hk4,  wh[4],  acc0);  acc1 = fmaf(hk5,  wh[5],  acc1);
        acc2 = fmaf(hk6,  wh[6],  acc2);  acc3 = fmaf(hk7,  wh[7],  acc3);
        acc0 = fmaf(hk8,  wh[8],  acc0);  acc1 = fmaf(hk9,  wh[9],  acc1);
        acc2 = fmaf(hk10, wh[10], acc2);  acc3 = fmaf(hk11, wh[11], acc3);
        acc0 = fmaf(hk12, wh[12], acc0);  acc1 = fmaf(hk13, wh[13], acc1);
        acc2 = fmaf(hk14, wh[14], acc2);
        float z = (acc0 + acc1) + (acc2 + acc3);
        float u = __builtin_amdgcn_exp2f(z);
        float r = fmaf(aa, __builtin_amdgcn_rcpf(1.0f + u), ab);  // activated gate
        float vi = quad_bcast<0>(r);
        float vf = quad_bcast<1>(r);
        float vg = quad_bcast<2>(r);
        float vo = quad_bcast<3>(r);
        c = fmaf(vf, c, vi * vg);
        float u2 = __builtin_amdgcn_exp2f(c * (-2.0f * LOG2E));
        float th = fmaf(2.0f, __builtin_amdgcn_rcpf(1.0f + u2), -1.0f);
        h = vo * th;                       // replicated in quad
        outp[(size_t)pos * 45] = h;
    };

    // deep software pipeline: gate rows 8 steps ahead, tokens 16 ahead
    int tbuf[8];
    float xbuf[8];
    #pragma unroll
    for (int u = 0; u < 8; ++u) tbuf[u] = tok(u);
    #pragma unroll
    for (int u = 0; u < 8; ++u) xbuf[u] = pj[(size_t)tbuf[u] * 64];
    #pragma unroll
    for (int u = 0; u < 8; ++u) tbuf[u] = tok(8 + u);

    int t = 0;
    for (; t + 8 <= L; t += 8) {
        #pragma unroll
        for (int u = 0; u < 8; ++u) {
            step(base + sgn * (t + u), xbuf[u]);
            xbuf[u] = pj[(size_t)tbuf[u] * 64];   // gate row for step t+8+u
            tbuf[u] = tok(t + 16 + u);            // token for step t+16+u
        }
    }
    for (int u = 0; t < L; ++t, ++u) step(base + sgn * t, xbuf[u]);
}

// Epilogue: in-place linear 30 -> 45 per (b,t) row; rows t >= L get just lin_b.
__global__ __launch_bounds__(256) void linear_kernel(
    const int* __restrict__ lengths,
    const float* __restrict__ lin_w, const float* __restrict__ lin_b,
    float* out, int T) {
    __shared__ float Ws[45 * 30];
    __shared__ float Bs[45];
    for (int i = threadIdx.x; i < 45 * 30; i += 256) Ws[i] = lin_w[i];
    if (threadIdx.x < 45) Bs[threadIdx.x] = lin_b[threadIdx.x];
    __syncthreads();
    const int b = blockIdx.y;
    const int t = blockIdx.x * 256 + threadIdx.x;
    if (t >= T) return;
    const int L = lengths[b];
    float* row = out + ((size_t)b * T + t) * 45;
    float y[45];
    if (t < L) {
        float x[30];
        #pragma unroll
        for (int k = 0; k < 30; ++k) x[k] = row[k];
        #pragma unroll
        for (int o = 0; o < 45; ++o) {
            float acc = Bs[o];
            #pragma unroll
            for (int k = 0; k < 30; ++k) acc = fmaf(x[k], Ws[o * 30 + k], acc);
            y[o] = acc;
        }
    } else {
        #pragma unroll
        for (int o = 0; o < 45; ++o) y[o] = Bs[o];
    }
    #pragma unroll
    for (int o = 0; o < 45; ++o) row[o] = y[o];
}

extern "C" void kernel_launch(void* const* d_in, const int* in_sizes, int n_in,
                              void* d_out, int out_size, void* d_ws, size_t ws_size,
                              hipStream_t stream) {
    const int* data      = (const int*)d_in[0];
    const int* lengths   = (const int*)d_in[2];
    const float* emb     = (const float*)d_in[3];
    const float* h0      = (const float*)d_in[4];
    const float* c0      = (const float*)d_in[5];
    const float* w_ih_f  = (const float*)d_in[6];
    const float* w_hh_f  = (const float*)d_in[7];
    const float* b_f     = (const float*)d_in[8];
    const float* w_ih_b  = (const float*)d_in[9];
    const float* w_hh_b  = (const float*)d_in[10];
    const float* b_b     = (const float*)d_in[11];
    const float* lin_w   = (const float*)d_in[12];
    const float* lin_b   = (const float*)d_in[13];
    float* out = (float*)d_out;

    const int T = in_sizes[0] / 64;
    const int V = in_sizes[3] / 15;
    float* proj = (float*)d_ws;   // 2*V*64 floats = 25.6 MB

    hipLaunchKernelGGL(proj_kernel, dim3((2 * V * 64 + 255) / 256), dim3(256), 0, stream,
                       emb, w_ih_f, b_f, w_ih_b, b_b, proj, V);
    hipLaunchKernelGGL(lstm_kernel, dim3(128), dim3(64), 0, stream,
                       data, lengths, proj, h0, c0, w_hh_f, w_hh_b, out, T, V);
    hipLaunchKernelGGL(linear_kernel, dim3((T + 255) / 256, 64), dim3(256), 0, stream,
                       lengths, lin_w, lin_b, out, T);
}

// Round 3
// 708.399 us; speedup vs baseline: 1.9944x; 1.0209x over previous
//
#include <hip/hip_runtime.h>
#include <cstdint>
#include <cstddef>

#define LOG2E 1.442695040888963f

__device__ __forceinline__ float rdlane(float v, int lane) {
    return __int_as_float(__builtin_amdgcn_readlane(__float_as_int(v), lane));
}

template <int Q>
__device__ __forceinline__ float quad_bcast(float v) {
    // quad_perm broadcast of lane Q within each quad of 4 lanes
    return __int_as_float(__builtin_amdgcn_update_dpp(
        0, __float_as_int(v), Q * 0x55, 0xF, 0xF, true));
}

// Precompute per-token gate inputs: proj[d][v][s] = m(s) * (b[row] + W_ih[row,:] . emb[v,:])
// s = 4*j + g lane-slot order, row = g*15+j (torch gate order i,f,g,o), stride 64 floats/row.
__global__ __launch_bounds__(256) void proj_kernel(
    const float* __restrict__ emb,
    const float* __restrict__ w_ih_f, const float* __restrict__ b_f,
    const float* __restrict__ w_ih_b, const float* __restrict__ b_b,
    float* __restrict__ proj, int V) {
    int gid = blockIdx.x * 256 + threadIdx.x;
    if (gid >= 2 * V * 64) return;
    int s = gid & 63;
    int v = (gid >> 6) % V;
    int d = gid / (V * 64);
    if (s >= 60) { proj[gid] = 0.0f; return; }
    int j = s >> 2, g = s & 3;
    int row = g * 15 + j;
    const float* w  = d ? w_ih_b : w_ih_f;
    const float* bv = d ? b_b   : b_f;
    float m = (g == 2) ? (-2.0f * LOG2E) : (-LOG2E);
    float acc = bv[row];
    #pragma unroll
    for (int k = 0; k < 15; ++k)
        acc = fmaf(emb[v * 15 + k], w[row * 15 + k], acc);
    proj[gid] = m * acc;
}

// One wave per (direction, sample). Lane = 4*j + g.
// Double-buffered block prefetch: gate rows loaded >=16 steps ahead, tokens >=32 ahead.
// Output stores: windowed (one coalesced 60-dword nt-store per 4 steps).
__global__ __launch_bounds__(64) void lstm_kernel(
    const int* __restrict__ data, const int* __restrict__ lengths,
    const float* __restrict__ proj,
    const float* __restrict__ h0, const float* __restrict__ c0,
    const float* __restrict__ w_hh_f, const float* __restrict__ w_hh_b,
    float* __restrict__ out, int T, int V) {
    const int lane = threadIdx.x;
    const int dir = blockIdx.x >> 6;
    const int b = blockIdx.x & 63;
    const int L = lengths[b];

    if (lane >= 60) return;   // exec stays 60 lanes for the whole loop

    const int j = lane >> 2;      // hidden unit 0..14
    const int g = lane & 3;       // 0=i 1=f 2=g(tanh) 3=o
    const int row = g * 15 + j;

    const float* whh = dir ? w_hh_b : w_hh_f;
    const float m  = (g == 2) ? (-2.0f * LOG2E) : (-LOG2E);
    const float aa = (g == 2) ? 2.0f : 1.0f;
    const float ab = (g == 2) ? -1.0f : 0.0f;

    const bool gm0 = (g == 0), gm1 = (g == 1), gm2 = (g == 2), gm3 = (g == 3);

    float wh[15];
    #pragma unroll
    for (int k = 0; k < 15; ++k) wh[k] = whh[row * 15 + k] * m;

    float h = h0[(dir * 64 + b) * 15 + j];   // replicated across quad
    float c = c0[(dir * 64 + b) * 15 + j];

    const int* drow = data + (size_t)b * T;
    const float* pj = proj + (size_t)dir * V * 64 + lane;
    const int sgn  = dir ? -1 : 1;
    const int base = dir ? (L - 1) : 0;   // pos(t) = base + sgn*t

    // windowed-store lane pointer: lane (j,g) owns output position (t0+g), column dir*15+j
    float* wp = out + ((size_t)b * T + (size_t)(dir ? (L - 1 - g) : g)) * 45 + dir * 15 + j;
    // tail per-step pointer (quad-duplicated)
    float* outp = out + ((size_t)b * T) * 45 + dir * 15 + j;

    auto tok = [&](int t) -> int {
        int tt = t < L ? t : L - 1;       // clamp prefetch past end
        return drow[base + sgn * tt];
    };

    auto step = [&](float xg) {
        float hk0 = rdlane(h, 0),  hk1 = rdlane(h, 4),  hk2 = rdlane(h, 8);
        float hk3 = rdlane(h, 12), hk4 = rdlane(h, 16), hk5 = rdlane(h, 20);
        float hk6 = rdlane(h, 24), hk7 = rdlane(h, 28), hk8 = rdlane(h, 32);
        float hk9 = rdlane(h, 36), hk10 = rdlane(h, 40), hk11 = rdlane(h, 44);
        float hk12 = rdlane(h, 48), hk13 = rdlane(h, 52), hk14 = rdlane(h, 56);
        float acc0 = xg, acc1 = 0.f, acc2 = 0.f, acc3 = 0.f;
        acc0 = fmaf(hk0,  wh[0],  acc0);  acc1 = fmaf(hk1,  wh[1],  acc1);
        acc2 = fmaf(hk2,  wh[2],  acc2);  acc3 = fmaf(hk3,  wh[3],  acc3);
        acc0 = fmaf(hk4,  wh[4],  acc0);  acc1 = fmaf(hk5,  wh[5],  acc1);
        acc2 = fmaf(hk6,  wh[6],  acc2);  acc3 = fmaf(hk7,  wh[7],  acc3);
        acc0 = fmaf(hk8,  wh[8],  acc0);  acc1 = fmaf(hk9,  wh[9],  acc1);
        acc2 = fmaf(hk10, wh[10], acc2);  acc3 = fmaf(hk11, wh[11], acc3);
        acc0 = fmaf(hk12, wh[12], acc0);  acc1 = fmaf(hk13, wh[13], acc1);
        acc2 = fmaf(hk14, wh[14], acc2);
        float z = (acc0 + acc1) + (acc2 + acc3);
        float u = __builtin_amdgcn_exp2f(z);
        float r = fmaf(aa, __builtin_amdgcn_rcpf(1.0f + u), ab);  // activated gate
        float vi = quad_bcast<0>(r);
        float vf = quad_bcast<1>(r);
        float vg = quad_bcast<2>(r);
        float vo = quad_bcast<3>(r);
        c = fmaf(vf, c, vi * vg);
        float u2 = __builtin_amdgcn_exp2f(c * (-2.0f * LOG2E));
        float th = fmaf(2.0f, __builtin_amdgcn_rcpf(1.0f + u2), -1.0f);
        h = vo * th;                       // replicated in quad
    };

    float xA[8], xB[8];
    int ta[8], tb[8];

    // prologue: xA = x[0..7], xB = x[8..15], ta = tok[16..23], tb = tok[24..31]
    #pragma unroll
    for (int u = 0; u < 8; ++u) ta[u] = tok(u);
    #pragma unroll
    for (int u = 0; u < 8; ++u) xA[u] = pj[(size_t)ta[u] * 64];
    #pragma unroll
    for (int u = 0; u < 8; ++u) ta[u] = tok(8 + u);
    #pragma unroll
    for (int u = 0; u < 8; ++u) xB[u] = pj[(size_t)ta[u] * 64];
    #pragma unroll
    for (int u = 0; u < 8; ++u) ta[u] = tok(16 + u);
    #pragma unroll
    for (int u = 0; u < 8; ++u) tb[u] = tok(24 + u);

    // 8 steps using buffer xb (loaded a full block ago), two 4-step store windows,
    // then refill xb for steps th+16.. via tokens tkb, and fetch tokens th+32..
    auto halfrun = [&](float (&xb)[8], int (&tkb)[8], int th) {
        float hc = h;
        step(xb[0]); hc = gm0 ? h : hc;
        step(xb[1]); hc = gm1 ? h : hc;
        step(xb[2]); hc = gm2 ? h : hc;
        step(xb[3]); hc = gm3 ? h : hc;
        __builtin_nontemporal_store(hc, wp + (ptrdiff_t)sgn * th * 45);
        step(xb[4]); hc = gm0 ? h : hc;
        step(xb[5]); hc = gm1 ? h : hc;
        step(xb[6]); hc = gm2 ? h : hc;
        step(xb[7]); hc = gm3 ? h : hc;
        __builtin_nontemporal_store(hc, wp + (ptrdiff_t)sgn * (th + 4) * 45);
        #pragma unroll
        for (int u = 0; u < 8; ++u) xb[u] = pj[(size_t)tkb[u] * 64];
        #pragma unroll
        for (int u = 0; u < 8; ++u) tkb[u] = tok(th + 32 + u);
    };

    int t = 0;
    for (; t + 16 <= L; t += 16) {
        halfrun(xA, ta, t);
        halfrun(xB, tb, t + 8);
    }
    // tail: xA holds x[t..t+7], xB holds x[t+8..t+15]; rem <= 15 steps
    #pragma unroll 1
    for (int u = 0; u < 8 && t < L; ++u, ++t) {
        step(xA[u]);
        outp[(size_t)(base + sgn * t) * 45] = h;
    }
    #pragma unroll 1
    for (int u = 0; u < 8 && t < L; ++u, ++t) {
        step(xB[u]);
        outp[(size_t)(base + sgn * t) * 45] = h;
    }
}

// Epilogue: in-place linear 30 -> 45 per (b,t) row; rows t >= L get just lin_b.
__global__ __launch_bounds__(256) void linear_kernel(
    const int* __restrict__ lengths,
    const float* __restrict__ lin_w, const float* __restrict__ lin_b,
    float* out, int T) {
    __shared__ float Ws[45 * 30];
    __shared__ float Bs[45];
    for (int i = threadIdx.x; i < 45 * 30; i += 256) Ws[i] = lin_w[i];
    if (threadIdx.x < 45) Bs[threadIdx.x] = lin_b[threadIdx.x];
    __syncthreads();
    const int b = blockIdx.y;
    const int t = blockIdx.x * 256 + threadIdx.x;
    if (t >= T) return;
    const int L = lengths[b];
    float* row = out + ((size_t)b * T + t) * 45;
    float y[45];
    if (t < L) {
        float x[30];
        #pragma unroll
        for (int k = 0; k < 30; ++k) x[k] = row[k];
        #pragma unroll
        for (int o = 0; o < 45; ++o) {
            float acc = Bs[o];
            #pragma unroll
            for (int k = 0; k < 30; ++k) acc = fmaf(x[k], Ws[o * 30 + k], acc);
            y[o] = acc;
        }
    } else {
        #pragma unroll
        for (int o = 0; o < 45; ++o) y[o] = Bs[o];
    }
    #pragma unroll
    for (int o = 0; o < 45; ++o) row[o] = y[o];
}

extern "C" void kernel_launch(void* const* d_in, const int* in_sizes, int n_in,
                              void* d_out, int out_size, void* d_ws, size_t ws_size,
                              hipStream_t stream) {
    const int* data      = (const int*)d_in[0];
    const int* lengths   = (const int*)d_in[2];
    const float* emb     = (const float*)d_in[3];
    const float* h0      = (const float*)d_in[4];
    const float* c0      = (const float*)d_in[5];
    const float* w_ih_f  = (const float*)d_in[6];
    const float* w_hh_f  = (const float*)d_in[7];
    const float* b_f     = (const float*)d_in[8];
    const float* w_ih_b  = (const float*)d_in[9];
    const float* w_hh_b  = (const float*)d_in[10];
    const float* b_b     = (const float*)d_in[11];
    const float* lin_w   = (const float*)d_in[12];
    const float* lin_b   = (const float*)d_in[13];
    float* out = (float*)d_out;

    const int T = in_sizes[0] / 64;
    const int V = in_sizes[3] / 15;
    float* proj = (float*)d_ws;   // 2*V*64 floats = 25.6 MB

    hipLaunchKernelGGL(proj_kernel, dim3((2 * V * 64 + 255) / 256), dim3(256), 0, stream,
                       emb, w_ih_f, b_f, w_ih_b, b_b, proj, V);
    hipLaunchKernelGGL(lstm_kernel, dim3(128), dim3(64), 0, stream,
                       data, lengths, proj, h0, c0, w_hh_f, w_hh_b, out, T, V);
    hipLaunchKernelGGL(linear_kernel, dim3((T + 255) / 256, 64), dim3(256), 0, stream,
                       lengths, lin_w, lin_b, out, T);
}